// Round 10
// baseline (340.001 us; speedup 1.0000x reference)
//
#include <hip/hip_runtime.h>
#include <cstdint>
#include <cstddef>

// Problem constants
#define SS    2304            // 48*48
#define OUT0  4718592         // 8*256*48*48
// probs region: 47,775,744 floats after OUT0

typedef short bf16x8 __attribute__((ext_vector_type(8)));
typedef float f32x4  __attribute__((ext_vector_type(4)));

__device__ __forceinline__ unsigned short f2bf(float f) {
    union { float f; unsigned int i; } v; v.f = f;
    unsigned int x = v.i;
    unsigned int r = x + 0x7fffu + ((x >> 16) & 1u);   // RNE
    return (unsigned short)(r >> 16);
}

// ---------------------------------------------------------------------------
// probs unit: 8 (i,j,h) tiles; probs[idx][k*48+l] = p1[h,i,k]*p2[h,j,l]
// no LDS, nontemporal float4 stores
// ---------------------------------------------------------------------------
__device__ __forceinline__ void probs_unit(int u, int t,
                                           const float* __restrict__ p1,
                                           const float* __restrict__ p2,
                                           float* __restrict__ probs) {
    #pragma unroll 2
    for (int tt = 0; tt < 8; ++tt) {
        int idx = u * 8 + tt;
        int h = idx % 9; int ij = idx / 9; int j = ij % 48; int i = ij / 48;
        const float* r1 = p1 + (h * 48 + i) * 48;
        const float4* r2 = (const float4*)(p2 + (h * 48 + j) * 48);
        f32x4* op = (f32x4*)(probs + (size_t)idx * SS);
        for (int g = t; g < 576; g += 256) {
            int k = g / 12, lq = g % 12;
            float s = r1[k];
            float4 q = r2[lq];
            f32x4 v; v[0] = s * q.x; v[1] = s * q.y; v[2] = s * q.z; v[3] = s * q.w;
            __builtin_nontemporal_store(v, op + g);
        }
    }
}

// ---------------------------------------------------------------------------
// K1 (softmax init only): 108 blocks x 256 thr (4 rows/block).
// p1/p2 fp32 (for probs) + p1b/p2b bf16 zero-padded-to-64 (MFMA staging).
// ---------------------------------------------------------------------------
__global__ __launch_bounds__(256) void k_pre(const float* __restrict__ centers,
                                             const float* __restrict__ spreads,
                                             float* __restrict__ p1, float* __restrict__ p2,
                                             unsigned short* __restrict__ p1b,
                                             unsigned short* __restrict__ p2b) {
    int t = threadIdx.x;
    int lane = t & 63, wave = t >> 6;
    int ridx = blockIdx.x * 4 + wave;       // 0..431
    int h = ridx / 48, r = ridx % 48;
    float a = spreads[h]; a = a * a;
    float mu1 = centers[2 * h + 0];
    float mu2 = centers[2 * h + 1];
    bool act = lane < 48;
    float dx = (float)(lane - r);
    float q  = -0.5f * a * dx * dx;
    float g1 = act ? (a * mu1 * dx + q) : -INFINITY;
    float g2 = act ? (a * mu2 * dx + q) : -INFINITY;
    float m1 = g1, m2 = g2;
    #pragma unroll
    for (int off = 32; off >= 1; off >>= 1) {
        m1 = fmaxf(m1, __shfl_xor(m1, off));
        m2 = fmaxf(m2, __shfl_xor(m2, off));
    }
    float e1 = act ? expf(g1 - m1) : 0.f;
    float e2 = act ? expf(g2 - m2) : 0.f;
    float s1 = e1, s2 = e2;
    #pragma unroll
    for (int off = 32; off >= 1; off >>= 1) {
        s1 += __shfl_xor(s1, off);
        s2 += __shfl_xor(s2, off);
    }
    float v1 = e1 / s1, v2 = e2 / s2;
    if (act) {
        p1[h * SS + r * 48 + lane] = v1;
        p2[h * SS + r * 48 + lane] = v2;
    }
    p1b[(h * 48 + r) * 64 + lane] = act ? f2bf(v1) : 0;
    p2b[(h * 48 + r) * 64 + lane] = act ? f2bf(v2) : 0;
}

// ---------------------------------------------------------------------------
// K2 (attention apply + probs writer + Wv pack, interleaved):
// grid 5184.  blk < 4608: even -> attn unit (blk>>1, 2304 units),
//                         odd  -> probs unit (blk>>1)           [if doProbs]
// blk in [4608,4896): probs units 2304..2591                    [if doProbs]
// blk in [4896,5184): Wv pack unit (kb = blk-4896)
// Interleaving keeps BW-streaming probs blocks co-resident with
// latency-bound attn blocks on every CU (attn launch has ~30us of idle BW).
// attn unit: per (h, b, d-octet): S^T = X*p1^T (mfma1 swapped, packed b64
//   spill), V^T = S*p2^T (mfma2).  Union LDS: S-LDS aliases Vbuf.
// ---------------------------------------------------------------------------
__global__ __launch_bounds__(256, 3) void k_attn(const float* __restrict__ hs,
                                                 const unsigned short* __restrict__ p1b,
                                                 const unsigned short* __restrict__ p2b,
                                                 unsigned short* __restrict__ AF,
                                                 const float* __restrict__ Wv,
                                                 unsigned short* __restrict__ WF,
                                                 const float* __restrict__ p1,
                                                 const float* __restrict__ p2,
                                                 float* __restrict__ probs,
                                                 int doProbs) {
    __shared__ unsigned short LSH[18432];   // 36864 B: S phase then Vbuf phase

    int blk = blockIdx.x;
    int t = threadIdx.x;

    if (blk >= 4896) {                      // ---- Wv pack unit ----
        int kb = blk - 4896;                // 0..287
        const float* src = Wv + (size_t)t * 2304 + kb * 8;
        float4 f0 = *(const float4*)src;
        float4 f1 = *(const float4*)(src + 4);
        uint4 o;
        o.x = (unsigned int)f2bf(f0.x) | ((unsigned int)f2bf(f0.y) << 16);
        o.y = (unsigned int)f2bf(f0.z) | ((unsigned int)f2bf(f0.w) << 16);
        o.z = (unsigned int)f2bf(f1.x) | ((unsigned int)f2bf(f1.y) << 16);
        o.w = (unsigned int)f2bf(f1.z) | ((unsigned int)f2bf(f1.w) << 16);
        *(uint4*)(WF + ((size_t)kb * 256 + t) * 8) = o;
        return;
    }
    if (blk >= 4608) {                      // ---- probs tail units ----
        if (doProbs) probs_unit(2304 + (blk - 4608), t, p1, p2, probs);
        return;
    }
    if (blk & 1) {                          // ---- probs interleaved units ----
        if (doProbs) probs_unit(blk >> 1, t, p1, p2, probs);
        return;
    }

    // ---- attn unit ----
    int u = blk >> 1;                       // 0..2303
    int h = u >> 8;
    int rem = u & 255;
    int b = rem >> 5, od = rem & 31;
    int d0 = od * 8;
    int kb = h * 32 + od;

    int lane = t & 63, wave = t >> 6;
    int l15 = lane & 15, quad = lane >> 4;

    // Preload p1 / p2 frags (A/B layouts symmetric for 16x16x32)
    const bf16x8* P1 = (const bf16x8*)(p1b + (size_t)h * 3072);
    const bf16x8* P2 = (const bf16x8*)(p2b + (size_t)h * 3072);
    bf16x8 pa[3][2], pb[3][2];
    #pragma unroll
    for (int tt = 0; tt < 3; ++tt)
        #pragma unroll
        for (int kt = 0; kt < 2; ++kt) {
            int ui = (tt * 16 + l15) * 8 + kt * 4 + quad;
            pa[tt][kt] = P1[ui];
            pb[tt][kt] = P2[ui];
        }

    // Phase 1: S-LDS = wave-private [i][l], pitch 80 bf16 (160 B)
    unsigned short* Sw = LSH + wave * 3840;
    // zero pad columns l = 48..63
    for (int z = lane; z < 384; z += 64) {
        int row = z >> 3;
        *(unsigned int*)(Sw + row * 80 + 48 + ((z & 7) << 1)) = 0u;
    }

    f32x4 a2k[2][9];        // V^T accs for both s-passes (held across phase 2)

    #pragma unroll
    for (int s = 0; s < 2; ++s) {
        int d = d0 + wave * 2 + s;
        size_t bd = (size_t)b * 256 + d;
        const float* X = hs + bd * SS;

        // X frags straight from fp32 hs (f2bf in-register); k>=48 zero
        bf16x8 bx[3][2];
        #pragma unroll
        for (int lt = 0; lt < 3; ++lt)
            #pragma unroll
            for (int kt = 0; kt < 2; ++kt) {
                uint4 o = {0u, 0u, 0u, 0u};
                if (kt == 0 || quad < 2) {
                    const float* px = X + (lt * 16 + l15) * 48 + kt * 32 + quad * 8;
                    float4 f0 = *(const float4*)px;
                    float4 f1 = *(const float4*)(px + 4);
                    o.x = (unsigned int)f2bf(f0.x) | ((unsigned int)f2bf(f0.y) << 16);
                    o.y = (unsigned int)f2bf(f0.z) | ((unsigned int)f2bf(f0.w) << 16);
                    o.z = (unsigned int)f2bf(f1.x) | ((unsigned int)f2bf(f1.y) << 16);
                    o.w = (unsigned int)f2bf(f1.z) | ((unsigned int)f2bf(f1.w) << 16);
                }
                bx[lt][kt] = __builtin_bit_cast(bf16x8, o);
            }

        // mfma1 (SWAPPED operands): D = S^T, rows = l, cols = i
        f32x4 a1[9];
        #pragma unroll
        for (int q = 0; q < 9; ++q) a1[q] = (f32x4){0.f, 0.f, 0.f, 0.f};
        #pragma unroll
        for (int lt = 0; lt < 3; ++lt)
            #pragma unroll
            for (int it = 0; it < 3; ++it) {
                a1[lt * 3 + it] = __builtin_amdgcn_mfma_f32_16x16x32_bf16(
                    bx[lt][0], pa[it][0], a1[lt * 3 + it], 0, 0, 0);
                a1[lt * 3 + it] = __builtin_amdgcn_mfma_f32_16x16x32_bf16(
                    bx[lt][1], pa[it][1], a1[lt * 3 + it], 0, 0, 0);
            }

        // S^T tile -> S[i][l] LDS: lane holds i = it*16+l15 (col), l = lt*16+quad*4+reg
        // -> one packed 8B write per tile (9 ds_write_b64)
        #pragma unroll
        for (int lt = 0; lt < 3; ++lt)
            #pragma unroll
            for (int it = 0; it < 3; ++it) {
                f32x4 v = a1[lt * 3 + it];
                uint2 u2;
                u2.x = (unsigned int)f2bf(v[0]) | ((unsigned int)f2bf(v[1]) << 16);
                u2.y = (unsigned int)f2bf(v[2]) | ((unsigned int)f2bf(v[3]) << 16);
                *(uint2*)(Sw + (it * 16 + l15) * 80 + lt * 16 + quad * 4) = u2;
            }

        // A2-frags: lane holds S[i = it*16+l15][kt*32+quad*8 ..+7]
        bf16x8 a2f[3][2];
        #pragma unroll
        for (int it = 0; it < 3; ++it)
            #pragma unroll
            for (int kt = 0; kt < 2; ++kt)
                a2f[it][kt] = *(const bf16x8*)(Sw + (it * 16 + l15) * 80 + kt * 32 + quad * 8);

        // mfma2: V^T[i,j] -> a2k[s]
        #pragma unroll
        for (int q = 0; q < 9; ++q) a2k[s][q] = (f32x4){0.f, 0.f, 0.f, 0.f};
        #pragma unroll
        for (int it = 0; it < 3; ++it)
            #pragma unroll
            for (int jt = 0; jt < 3; ++jt) {
                a2k[s][it * 3 + jt] = __builtin_amdgcn_mfma_f32_16x16x32_bf16(
                    a2f[it][0], pb[jt][0], a2k[s][it * 3 + jt], 0, 0, 0);
                a2k[s][it * 3 + jt] = __builtin_amdgcn_mfma_f32_16x16x32_bf16(
                    a2f[it][1], pb[jt][1], a2k[s][it * 3 + jt], 0, 0, 0);
            }
    }

    // Phase 2: Vbuf = LSH as [kk][2304] (aliases S-LDS; S fully consumed)
    __syncthreads();
    #pragma unroll
    for (int s = 0; s < 2; ++s) {
        int kk = wave * 2 + s;
        #pragma unroll
        for (int it = 0; it < 3; ++it)
            #pragma unroll
            for (int jt = 0; jt < 3; ++jt) {
                f32x4 v = a2k[s][it * 3 + jt];
                uint2 u2;
                u2.x = (unsigned int)f2bf(v[0]) | ((unsigned int)f2bf(v[1]) << 16);
                u2.y = (unsigned int)f2bf(v[2]) | ((unsigned int)f2bf(v[3]) << 16);
                int m = (jt * 16 + l15) * 48 + it * 16 + quad * 4;
                *(uint2*)(LSH + kk * 2304 + m) = u2;
            }
    }
    __syncthreads();

    // Epilogue: AF[b][kb][m][kk] <- Vbuf[kk][m], full-16B uint4 stores
    const uint2* Vr = (const uint2*)LSH;     // 576 uint2 per kk row
    uint4* AFq = (uint4*)AF;
    size_t abase = (size_t)(b * 288 + kb) * 2304;
    for (int g = t; g < 576; g += 256) {
        uint2 rk[8];
        #pragma unroll
        for (int kk = 0; kk < 8; ++kk) rk[kk] = Vr[kk * 576 + g];
        #pragma unroll
        for (int mi = 0; mi < 4; ++mi) {
            unsigned int sel = (mi & 1) ? 0x07060302u : 0x05040100u;
            uint4 o;
            if (mi < 2) {
                o.x = __builtin_amdgcn_perm(rk[1].x, rk[0].x, sel);
                o.y = __builtin_amdgcn_perm(rk[3].x, rk[2].x, sel);
                o.z = __builtin_amdgcn_perm(rk[5].x, rk[4].x, sel);
                o.w = __builtin_amdgcn_perm(rk[7].x, rk[6].x, sel);
            } else {
                o.x = __builtin_amdgcn_perm(rk[1].y, rk[0].y, sel);
                o.y = __builtin_amdgcn_perm(rk[3].y, rk[2].y, sel);
                o.z = __builtin_amdgcn_perm(rk[5].y, rk[4].y, sel);
                o.w = __builtin_amdgcn_perm(rk[7].y, rk[6].y, sel);
            }
            AFq[abase + g * 4 + mi] = o;
        }
    }
}

// ---------------------------------------------------------------------------
// K3 (tail): gemmC only.  out[b][e][m] = sum_k AF(k,m)*W(e,k) + vb[e].
//   block = (b, mb): M-tile 32, N = 256 (wave e0 = wave*64) -> AF fetched ONCE.
// ---------------------------------------------------------------------------
__global__ __launch_bounds__(256) void k_tail(const unsigned short* __restrict__ AF,
                                              const unsigned short* __restrict__ WF,
                                              const float* __restrict__ vb,
                                              float* __restrict__ out) {
    int blk = blockIdx.x;
    int t = threadIdx.x;

    int b = blk / 72, mb = blk % 72;
    int lane = t & 63, wave = t >> 6;
    int l15 = lane & 15, quad = lane >> 4;
    int m0 = mb * 32;
    int e0 = wave * 64;

    const bf16x8* pa = (const bf16x8*)AF + (size_t)b * 288 * 2304
                       + (size_t)quad * 2304 + m0 + l15;
    const bf16x8* pw = (const bf16x8*)WF + (size_t)quad * 256 + e0 + l15;

    f32x4 acc[2][4];
    #pragma unroll
    for (int i = 0; i < 2; i++)
        #pragma unroll
        for (int j = 0; j < 4; j++) acc[i][j] = (f32x4){0.f, 0.f, 0.f, 0.f};

    bf16x8 a_cur[2], w_cur[4], a_nxt[2], w_nxt[4];
    a_cur[0] = pa[0];  a_cur[1] = pa[16];
    w_cur[0] = pw[0];  w_cur[1] = pw[16]; w_cur[2] = pw[32]; w_cur[3] = pw[48];

    for (int c = 0; c < 72; ++c) {
        if (c < 71) {
            a_nxt[0] = pa[9216];      a_nxt[1] = pa[9216 + 16];
            w_nxt[0] = pw[1024];      w_nxt[1] = pw[1024 + 16];
            w_nxt[2] = pw[1024 + 32]; w_nxt[3] = pw[1024 + 48];
        }
        #pragma unroll
        for (int tm = 0; tm < 2; ++tm)
            #pragma unroll
            for (int te = 0; te < 4; ++te)
                acc[tm][te] = __builtin_amdgcn_mfma_f32_16x16x32_bf16(
                    a_cur[tm], w_cur[te], acc[tm][te], 0, 0, 0);
        a_cur[0] = a_nxt[0]; a_cur[1] = a_nxt[1];
        w_cur[0] = w_nxt[0]; w_cur[1] = w_nxt[1]; w_cur[2] = w_nxt[2]; w_cur[3] = w_nxt[3];
        pa += 9216; pw += 1024;
    }

    size_t obase = (size_t)b * 589824;
    #pragma unroll
    for (int te = 0; te < 4; ++te) {
        int e = e0 + te * 16 + l15;
        float bias = vb[e];
        #pragma unroll
        for (int tm = 0; tm < 2; ++tm) {
            int m = m0 + tm * 16 + quad * 4;
            float4 v;
            v.x = acc[tm][te][0] + bias;
            v.y = acc[tm][te][1] + bias;
            v.z = acc[tm][te][2] + bias;
            v.w = acc[tm][te][3] + bias;
            *(float4*)(out + obase + (size_t)e * SS + m) = v;
        }
    }
}

// Separate probs kernel for the small-workspace fallback path
__global__ __launch_bounds__(256) void k_probs_sep(const float* __restrict__ p1,
                                                   const float* __restrict__ p2,
                                                   float* __restrict__ probs) {
    probs_unit(blockIdx.x, threadIdx.x, p1, p2, probs);
}

// ---------------------------------------------------------------------------
extern "C" void kernel_launch(void* const* d_in, const int* in_sizes, int n_in,
                              void* d_out, int out_size, void* d_ws, size_t ws_size,
                              hipStream_t stream) {
    const float* hs      = (const float*)d_in[0];
    const float* centers = (const float*)d_in[1];
    const float* spreads = (const float*)d_in[2];
    const float* Wv      = (const float*)d_in[3];
    const float* vbias   = (const float*)d_in[4];

    float* out   = (float*)d_out;
    float* probs = out + OUT0;                   // 47,775,744 floats (191 MB)

    const size_t needBig = 87000000;             // bytes (AF+WF+p1b/p2b+p1/p2)
    bool big = ws_size >= needBig;

    unsigned short *AF, *WF, *p1b, *p2b;
    float *p1, *p2;
    if (big) {
        unsigned short* w = (unsigned short*)d_ws;
        AF  = w;                       // 42,467,328 bf16 (84.9 MB)
        WF  = AF + 42467328;           // 589,824 bf16
        p1b = WF + 589824;             // 27,648 bf16 each
        p2b = p1b + 27648;
        p1  = (float*)(p2b + 27648);   // 20,736 f32 each
        p2  = p1 + 20736;
    } else {
        p1  = (float*)d_ws;
        p2  = p1 + 20736;
        p1b = (unsigned short*)(p2 + 20736);
        p2b = p1b + 27648;
        AF  = (unsigned short*)probs;  // carve probs region; probs written last
        WF  = AF + 42467328;
    }

    k_pre<<<108, 256, 0, stream>>>(centers, spreads, p1, p2, p1b, p2b);
    if (big) {
        // probs interleaved with attn (fills attn's idle BW); tail = gemmC only
        k_attn<<<5184, 256, 0, stream>>>(hs, p1b, p2b, AF, Wv, WF, p1, p2, probs, 1);
        k_tail<<<576, 256, 0, stream>>>(AF, WF, vbias, out);
    } else {
        // AF aliases probs region: probs must be written last
        k_attn<<<5184, 256, 0, stream>>>(hs, p1b, p2b, AF, Wv, WF, p1, p2, probs, 0);
        k_tail<<<576, 256, 0, stream>>>(AF, WF, vbias, out);
        k_probs_sep<<<2592, 256, 0, stream>>>(p1, p2, probs);
    }
}

// Round 11
// 302.011 us; speedup vs baseline: 1.1258x; 1.1258x over previous
//
#include <hip/hip_runtime.h>
#include <cstdint>
#include <cstddef>

// Problem constants
#define SS    2304            // 48*48
#define OUT0  4718592         // 8*256*48*48
// probs region: 47,775,744 floats after OUT0

typedef short bf16x8 __attribute__((ext_vector_type(8)));
typedef float f32x4  __attribute__((ext_vector_type(4)));

__device__ __forceinline__ unsigned short f2bf(float f) {
    union { float f; unsigned int i; } v; v.f = f;
    unsigned int x = v.i;
    unsigned int r = x + 0x7fffu + ((x >> 16) & 1u);   // RNE
    return (unsigned short)(r >> 16);
}

// ---------------------------------------------------------------------------
// K1 (softmax init only): 108 blocks x 256 thr (4 rows/block).
// p1/p2 fp32 (for probs) + p1b/p2b bf16 zero-padded-to-64 (MFMA staging).
// ---------------------------------------------------------------------------
__global__ __launch_bounds__(256) void k_pre(const float* __restrict__ centers,
                                             const float* __restrict__ spreads,
                                             float* __restrict__ p1, float* __restrict__ p2,
                                             unsigned short* __restrict__ p1b,
                                             unsigned short* __restrict__ p2b) {
    int t = threadIdx.x;
    int lane = t & 63, wave = t >> 6;
    int ridx = blockIdx.x * 4 + wave;       // 0..431
    int h = ridx / 48, r = ridx % 48;
    float a = spreads[h]; a = a * a;
    float mu1 = centers[2 * h + 0];
    float mu2 = centers[2 * h + 1];
    bool act = lane < 48;
    float dx = (float)(lane - r);
    float q  = -0.5f * a * dx * dx;
    float g1 = act ? (a * mu1 * dx + q) : -INFINITY;
    float g2 = act ? (a * mu2 * dx + q) : -INFINITY;
    float m1 = g1, m2 = g2;
    #pragma unroll
    for (int off = 32; off >= 1; off >>= 1) {
        m1 = fmaxf(m1, __shfl_xor(m1, off));
        m2 = fmaxf(m2, __shfl_xor(m2, off));
    }
    float e1 = act ? expf(g1 - m1) : 0.f;
    float e2 = act ? expf(g2 - m2) : 0.f;
    float s1 = e1, s2 = e2;
    #pragma unroll
    for (int off = 32; off >= 1; off >>= 1) {
        s1 += __shfl_xor(s1, off);
        s2 += __shfl_xor(s2, off);
    }
    float v1 = e1 / s1, v2 = e2 / s2;
    if (act) {
        p1[h * SS + r * 48 + lane] = v1;
        p2[h * SS + r * 48 + lane] = v2;
    }
    p1b[(h * 48 + r) * 64 + lane] = act ? f2bf(v1) : 0;
    p2b[(h * 48 + r) * 64 + lane] = act ? f2bf(v2) : 0;
}

// ---------------------------------------------------------------------------
// K2 (attention apply + Wv pack):
// blocks < 2304: per (h, b, d-octet): S^T = X*p1^T (mfma1, swapped operands ->
//   lane holds 4 consecutive l for fixed i -> packed ds_write_b64 spill),
//   V^T = S*p2^T (mfma2).  hs read directly as fp32, f2bf in-register.
//   Union LDS: S-LDS (wave-private 48x80-pitch, phase 1) aliases Vbuf.
// blocks >= 2304: Wv fp32 [e][k] -> WF bf16 [kb][e][kk] (overlaps attn).
// 3 blocks/CU (36.9 KB LDS).
// NOTE (R10 lesson): do NOT put no-LDS worker blocks (probs) in this kernel —
// the static 36.9 KB LDS allocation applies to every block regardless of
// branch, capping their occupancy and displacing attn blocks.
// ---------------------------------------------------------------------------
__global__ __launch_bounds__(256, 3) void k_attn(const float* __restrict__ hs,
                                                 const unsigned short* __restrict__ p1b,
                                                 const unsigned short* __restrict__ p2b,
                                                 unsigned short* __restrict__ AF,
                                                 const float* __restrict__ Wv,
                                                 unsigned short* __restrict__ WF) {
    __shared__ unsigned short LSH[18432];   // 36864 B: S phase then Vbuf phase

    int blk = blockIdx.x;
    int t = threadIdx.x;

    if (blk >= 2304) {                      // ---- Wv pack unit ----
        int kb = blk - 2304;                // 0..287
        const float* src = Wv + (size_t)t * 2304 + kb * 8;
        float4 f0 = *(const float4*)src;
        float4 f1 = *(const float4*)(src + 4);
        uint4 o;
        o.x = (unsigned int)f2bf(f0.x) | ((unsigned int)f2bf(f0.y) << 16);
        o.y = (unsigned int)f2bf(f0.z) | ((unsigned int)f2bf(f0.w) << 16);
        o.z = (unsigned int)f2bf(f1.x) | ((unsigned int)f2bf(f1.y) << 16);
        o.w = (unsigned int)f2bf(f1.z) | ((unsigned int)f2bf(f1.w) << 16);
        *(uint4*)(WF + ((size_t)kb * 256 + t) * 8) = o;
        return;
    }

    int h = blk >> 8;
    int rem = blk & 255;
    int b = rem >> 5, od = rem & 31;
    int d0 = od * 8;
    int kb = h * 32 + od;

    int lane = t & 63, wave = t >> 6;
    int l15 = lane & 15, quad = lane >> 4;

    // Preload p1 / p2 frags (A/B layouts symmetric for 16x16x32)
    const bf16x8* P1 = (const bf16x8*)(p1b + (size_t)h * 3072);
    const bf16x8* P2 = (const bf16x8*)(p2b + (size_t)h * 3072);
    bf16x8 pa[3][2], pb[3][2];
    #pragma unroll
    for (int tt = 0; tt < 3; ++tt)
        #pragma unroll
        for (int kt = 0; kt < 2; ++kt) {
            int u = (tt * 16 + l15) * 8 + kt * 4 + quad;
            pa[tt][kt] = P1[u];
            pb[tt][kt] = P2[u];
        }

    // Phase 1: S-LDS = wave-private [i][l], pitch 80 bf16 (160 B)
    unsigned short* Sw = LSH + wave * 3840;
    // zero pad columns l = 48..63
    for (int z = lane; z < 384; z += 64) {
        int row = z >> 3;
        *(unsigned int*)(Sw + row * 80 + 48 + ((z & 7) << 1)) = 0u;
    }

    f32x4 a2k[2][9];        // V^T accs for both s-passes (held across phase 2)

    #pragma unroll
    for (int s = 0; s < 2; ++s) {
        int d = d0 + wave * 2 + s;
        size_t bd = (size_t)b * 256 + d;
        const float* X = hs + bd * SS;

        // X frags straight from fp32 hs (f2bf in-register); k>=48 zero
        bf16x8 bx[3][2];
        #pragma unroll
        for (int lt = 0; lt < 3; ++lt)
            #pragma unroll
            for (int kt = 0; kt < 2; ++kt) {
                uint4 o = {0u, 0u, 0u, 0u};
                if (kt == 0 || quad < 2) {
                    const float* px = X + (lt * 16 + l15) * 48 + kt * 32 + quad * 8;
                    float4 f0 = *(const float4*)px;
                    float4 f1 = *(const float4*)(px + 4);
                    o.x = (unsigned int)f2bf(f0.x) | ((unsigned int)f2bf(f0.y) << 16);
                    o.y = (unsigned int)f2bf(f0.z) | ((unsigned int)f2bf(f0.w) << 16);
                    o.z = (unsigned int)f2bf(f1.x) | ((unsigned int)f2bf(f1.y) << 16);
                    o.w = (unsigned int)f2bf(f1.z) | ((unsigned int)f2bf(f1.w) << 16);
                }
                bx[lt][kt] = __builtin_bit_cast(bf16x8, o);
            }

        // mfma1 (SWAPPED operands): D = S^T, rows = l, cols = i
        f32x4 a1[9];
        #pragma unroll
        for (int q = 0; q < 9; ++q) a1[q] = (f32x4){0.f, 0.f, 0.f, 0.f};
        #pragma unroll
        for (int lt = 0; lt < 3; ++lt)
            #pragma unroll
            for (int it = 0; it < 3; ++it) {
                a1[lt * 3 + it] = __builtin_amdgcn_mfma_f32_16x16x32_bf16(
                    bx[lt][0], pa[it][0], a1[lt * 3 + it], 0, 0, 0);
                a1[lt * 3 + it] = __builtin_amdgcn_mfma_f32_16x16x32_bf16(
                    bx[lt][1], pa[it][1], a1[lt * 3 + it], 0, 0, 0);
            }

        // S^T tile -> S[i][l] LDS: lane holds i = it*16+l15 (col), l = lt*16+quad*4+reg
        // -> one packed 8B write per tile (9 ds_write_b64 instead of 36 ds_write_u16)
        #pragma unroll
        for (int lt = 0; lt < 3; ++lt)
            #pragma unroll
            for (int it = 0; it < 3; ++it) {
                f32x4 v = a1[lt * 3 + it];
                uint2 u2;
                u2.x = (unsigned int)f2bf(v[0]) | ((unsigned int)f2bf(v[1]) << 16);
                u2.y = (unsigned int)f2bf(v[2]) | ((unsigned int)f2bf(v[3]) << 16);
                *(uint2*)(Sw + (it * 16 + l15) * 80 + lt * 16 + quad * 4) = u2;
            }

        // A2-frags: lane holds S[i = it*16+l15][kt*32+quad*8 ..+7]
        bf16x8 a2f[3][2];
        #pragma unroll
        for (int it = 0; it < 3; ++it)
            #pragma unroll
            for (int kt = 0; kt < 2; ++kt)
                a2f[it][kt] = *(const bf16x8*)(Sw + (it * 16 + l15) * 80 + kt * 32 + quad * 8);

        // mfma2: V^T[i,j] -> a2k[s]
        #pragma unroll
        for (int q = 0; q < 9; ++q) a2k[s][q] = (f32x4){0.f, 0.f, 0.f, 0.f};
        #pragma unroll
        for (int it = 0; it < 3; ++it)
            #pragma unroll
            for (int jt = 0; jt < 3; ++jt) {
                a2k[s][it * 3 + jt] = __builtin_amdgcn_mfma_f32_16x16x32_bf16(
                    a2f[it][0], pb[jt][0], a2k[s][it * 3 + jt], 0, 0, 0);
                a2k[s][it * 3 + jt] = __builtin_amdgcn_mfma_f32_16x16x32_bf16(
                    a2f[it][1], pb[jt][1], a2k[s][it * 3 + jt], 0, 0, 0);
            }
    }

    // Phase 2: Vbuf = LSH as [kk][2304] (aliases S-LDS; S fully consumed)
    __syncthreads();
    #pragma unroll
    for (int s = 0; s < 2; ++s) {
        int kk = wave * 2 + s;
        #pragma unroll
        for (int it = 0; it < 3; ++it)
            #pragma unroll
            for (int jt = 0; jt < 3; ++jt) {
                f32x4 v = a2k[s][it * 3 + jt];
                uint2 u2;
                u2.x = (unsigned int)f2bf(v[0]) | ((unsigned int)f2bf(v[1]) << 16);
                u2.y = (unsigned int)f2bf(v[2]) | ((unsigned int)f2bf(v[3]) << 16);
                int m = (jt * 16 + l15) * 48 + it * 16 + quad * 4;
                *(uint2*)(LSH + kk * 2304 + m) = u2;
            }
    }
    __syncthreads();

    // Epilogue: AF[b][kb][m][kk] <- Vbuf[kk][m], full-16B uint4 stores
    const uint2* Vr = (const uint2*)LSH;     // 576 uint2 per kk row
    uint4* AFq = (uint4*)AF;
    size_t abase = (size_t)(b * 288 + kb) * 2304;
    for (int g = t; g < 576; g += 256) {
        uint2 rk[8];
        #pragma unroll
        for (int kk = 0; kk < 8; ++kk) rk[kk] = Vr[kk * 576 + g];
        #pragma unroll
        for (int mi = 0; mi < 4; ++mi) {
            unsigned int sel = (mi & 1) ? 0x07060302u : 0x05040100u;
            uint4 o;
            if (mi < 2) {
                o.x = __builtin_amdgcn_perm(rk[1].x, rk[0].x, sel);
                o.y = __builtin_amdgcn_perm(rk[3].x, rk[2].x, sel);
                o.z = __builtin_amdgcn_perm(rk[5].x, rk[4].x, sel);
                o.w = __builtin_amdgcn_perm(rk[7].x, rk[6].x, sel);
            } else {
                o.x = __builtin_amdgcn_perm(rk[1].y, rk[0].y, sel);
                o.y = __builtin_amdgcn_perm(rk[3].y, rk[2].y, sel);
                o.z = __builtin_amdgcn_perm(rk[5].y, rk[4].y, sel);
                o.w = __builtin_amdgcn_perm(rk[7].y, rk[6].y, sel);
            }
            AFq[abase + g * 4 + mi] = o;
        }
    }
}

// ---------------------------------------------------------------------------
// probs unit: 8 (i,j,h) tiles; probs[idx][k*48+l] = p1[h,i,k]*p2[h,j,l]
// no LDS, nontemporal float4 stores
// ---------------------------------------------------------------------------
__device__ __forceinline__ void probs_unit(int u, int t,
                                           const float* __restrict__ p1,
                                           const float* __restrict__ p2,
                                           float* __restrict__ probs) {
    #pragma unroll 2
    for (int tt = 0; tt < 8; ++tt) {
        int idx = u * 8 + tt;
        int h = idx % 9; int ij = idx / 9; int j = ij % 48; int i = ij / 48;
        const float* r1 = p1 + (h * 48 + i) * 48;
        const float4* r2 = (const float4*)(p2 + (h * 48 + j) * 48);
        f32x4* op = (f32x4*)(probs + (size_t)idx * SS);
        for (int g = t; g < 576; g += 256) {
            int k = g / 12, lq = g % 12;
            float s = r1[k];
            float4 q = r2[lq];
            f32x4 v; v[0] = s * q.x; v[1] = s * q.y; v[2] = s * q.z; v[3] = s * q.w;
            __builtin_nontemporal_store(v, op + g);
        }
    }
}

// ---------------------------------------------------------------------------
// K3 (tail): blocks 0..575 = gemmC, blocks 576.. = probs writer.  No LDS in
// either role -> both co-schedule at high occupancy (probs fills BW while
// gemmC blocks fetch).
// gemmC: out[b][e][m] = sum_k AF(k,m)*W(e,k) + vb[e].
//   block = (b, mb): M-tile 32, N = 256 (wave e0 = wave*64) -> AF fetched ONCE.
// ---------------------------------------------------------------------------
__global__ __launch_bounds__(256) void k_tail(const unsigned short* __restrict__ AF,
                                              const unsigned short* __restrict__ WF,
                                              const float* __restrict__ vb,
                                              float* __restrict__ out,
                                              const float* __restrict__ p1,
                                              const float* __restrict__ p2,
                                              float* __restrict__ probs) {
    int blk = blockIdx.x;
    int t = threadIdx.x;

    if (blk >= 576) {               // probs writer
        probs_unit(blk - 576, t, p1, p2, probs);
        return;
    }

    int b = blk / 72, mb = blk % 72;
    int lane = t & 63, wave = t >> 6;
    int l15 = lane & 15, quad = lane >> 4;
    int m0 = mb * 32;
    int e0 = wave * 64;

    const bf16x8* pa = (const bf16x8*)AF + (size_t)b * 288 * 2304
                       + (size_t)quad * 2304 + m0 + l15;
    const bf16x8* pw = (const bf16x8*)WF + (size_t)quad * 256 + e0 + l15;

    f32x4 acc[2][4];
    #pragma unroll
    for (int i = 0; i < 2; i++)
        #pragma unroll
        for (int j = 0; j < 4; j++) acc[i][j] = (f32x4){0.f, 0.f, 0.f, 0.f};

    bf16x8 a_cur[2], w_cur[4], a_nxt[2], w_nxt[4];
    a_cur[0] = pa[0];  a_cur[1] = pa[16];
    w_cur[0] = pw[0];  w_cur[1] = pw[16]; w_cur[2] = pw[32]; w_cur[3] = pw[48];

    for (int c = 0; c < 72; ++c) {
        if (c < 71) {
            a_nxt[0] = pa[9216];      a_nxt[1] = pa[9216 + 16];
            w_nxt[0] = pw[1024];      w_nxt[1] = pw[1024 + 16];
            w_nxt[2] = pw[1024 + 32]; w_nxt[3] = pw[1024 + 48];
        }
        #pragma unroll
        for (int tm = 0; tm < 2; ++tm)
            #pragma unroll
            for (int te = 0; te < 4; ++te)
                acc[tm][te] = __builtin_amdgcn_mfma_f32_16x16x32_bf16(
                    a_cur[tm], w_cur[te], acc[tm][te], 0, 0, 0);
        a_cur[0] = a_nxt[0]; a_cur[1] = a_nxt[1];
        w_cur[0] = w_nxt[0]; w_cur[1] = w_nxt[1]; w_cur[2] = w_nxt[2]; w_cur[3] = w_nxt[3];
        pa += 9216; pw += 1024;
    }

    size_t obase = (size_t)b * 589824;
    #pragma unroll
    for (int te = 0; te < 4; ++te) {
        int e = e0 + te * 16 + l15;
        float bias = vb[e];
        #pragma unroll
        for (int tm = 0; tm < 2; ++tm) {
            int m = m0 + tm * 16 + quad * 4;
            float4 v;
            v.x = acc[tm][te][0] + bias;
            v.y = acc[tm][te][1] + bias;
            v.z = acc[tm][te][2] + bias;
            v.w = acc[tm][te][3] + bias;
            *(float4*)(out + obase + (size_t)e * SS + m) = v;
        }
    }
}

// Separate probs kernel for the small-workspace fallback path
__global__ __launch_bounds__(256) void k_probs_sep(const float* __restrict__ p1,
                                                   const float* __restrict__ p2,
                                                   float* __restrict__ probs) {
    probs_unit(blockIdx.x, threadIdx.x, p1, p2, probs);
}

// ---------------------------------------------------------------------------
extern "C" void kernel_launch(void* const* d_in, const int* in_sizes, int n_in,
                              void* d_out, int out_size, void* d_ws, size_t ws_size,
                              hipStream_t stream) {
    const float* hs      = (const float*)d_in[0];
    const float* centers = (const float*)d_in[1];
    const float* spreads = (const float*)d_in[2];
    const float* Wv      = (const float*)d_in[3];
    const float* vbias   = (const float*)d_in[4];

    float* out   = (float*)d_out;
    float* probs = out + OUT0;                   // 47,775,744 floats (191 MB)

    const size_t needBig = 87000000;             // bytes (AF+WF+p1b/p2b+p1/p2)
    bool big = ws_size >= needBig;

    unsigned short *AF, *WF, *p1b, *p2b;
    float *p1, *p2;
    if (big) {
        unsigned short* w = (unsigned short*)d_ws;
        AF  = w;                       // 42,467,328 bf16 (84.9 MB)
        WF  = AF + 42467328;           // 589,824 bf16
        p1b = WF + 589824;             // 27,648 bf16 each
        p2b = p1b + 27648;
        p1  = (float*)(p2b + 27648);   // 20,736 f32 each
        p2  = p1 + 20736;
    } else {
        p1  = (float*)d_ws;
        p2  = p1 + 20736;
        p1b = (unsigned short*)(p2 + 20736);
        p2b = p1b + 27648;
        AF  = (unsigned short*)probs;  // carve probs region; probs written last
        WF  = AF + 42467328;
    }

    k_pre<<<108, 256, 0, stream>>>(centers, spreads, p1, p2, p1b, p2b);
    k_attn<<<2304 + 288, 256, 0, stream>>>(hs, p1b, p2b, AF, Wv, WF);
    if (big) {
        k_tail<<<576 + 2592, 256, 0, stream>>>(AF, WF, vbias, out, p1, p2, probs);
    } else {
        k_tail<<<576, 256, 0, stream>>>(AF, WF, vbias, out, p1, p2, probs);
        k_probs_sep<<<2592, 256, 0, stream>>>(p1, p2, probs);
    }
}